// Round 1
// baseline (469.452 us; speedup 1.0000x reference)
//
#include <hip/hip_runtime.h>

typedef __attribute__((ext_vector_type(8))) short short8;
typedef __attribute__((ext_vector_type(4))) short short4v;
typedef __attribute__((ext_vector_type(4))) float f32x4;

#define MFMA(a, b, c) __builtin_amdgcn_mfma_f32_16x16x32_bf16(a, b, c, 0, 0, 0)

__device__ __forceinline__ short f2bf(float f) {
  union { float f; unsigned u; } v;
  v.f = f;
  unsigned r = v.u + 0x7fffu + ((v.u >> 16) & 1u);
  return (short)(r >> 16);
}

// strides in shorts (all chosen: byte stride %16==0 for b128 alignment,
// dword stride %32==4 -> 2-way bank aliasing (free per m136))
#define XS_STR 392    // x window / attn-out stride (384+8)
#define QK_STR 1160   // qkv stride (1152+8)
#define P_STR  72     // P scratch stride (64+8)
#define AO_STR 392

__global__ void prep_weights(const float* __restrict__ wqkv,
                             const float* __restrict__ wout,
                             short* __restrict__ wqkvT,
                             short* __restrict__ woutT) {
  int i = blockIdx.x * 256 + threadIdx.x;
  if (i < 1152 * 384) {                  // wqkvT[n][k] = wqkv[k][n]
    int n = i / 384, k = i - (i / 384) * 384;
    wqkvT[i] = f2bf(wqkv[k * 1152 + n]);
  }
  if (i < 384 * 384) {                   // woutT[n][k] = wout[k][n]
    int n = i / 384, k = i - (i / 384) * 384;
    woutT[i] = f2bf(wout[k * 384 + n]);
  }
}

__global__ __launch_bounds__(512, 2) void swin_fused(
    const float* __restrict__ x, const short* __restrict__ wqkvT,
    const float* __restrict__ pos_emb, const short* __restrict__ woutT,
    const float* __restrict__ bout, float* __restrict__ out) {

  __shared__ short xs[49 * XS_STR];   // 38,416 B; aliased later: P scratch (8 waves x 32x72)
  __shared__ short qkv[49 * QK_STR];  // 113,680 B; aliased later: attn-out [49][392]
  __shared__ float pe[169];           // pos_emb 13x13

  const int tid = threadIdx.x;
  const int lane = tid & 63;
  const int wv = tid >> 6;     // wave 0..7
  const int l15 = lane & 15;
  const int lhi = lane >> 4;   // 0..3

  const int bw = blockIdx.x;
  const int batch = bw >> 6;
  const int win = bw & 63;
  const int wy = win >> 3, wx = win & 7;

  if (tid < 169) pe[tid] = pos_emb[tid];

  const size_t xbase = (size_t)batch * (56 * 56 * 384);
  const short8 zero8 = {0, 0, 0, 0, 0, 0, 0, 0};
  const f32x4 zf = {0.f, 0.f, 0.f, 0.f};

  // ---------------- Phase 1: load shifted x window -> xs (bf16) ----------------
  for (int t = tid; t < 49 * 96; t += 512) {
    int tok = t / 96;
    int seg = t - tok * 96;
    int iy = (tok * 37) >> 8;          // tok/7 (exact for 0..63)
    int ix = tok - iy * 7;
    int r = wy * 7 + iy + 3; if (r >= 56) r -= 56;   // roll(-3) load mapping
    int c = wx * 7 + ix + 3; if (c >= 56) c -= 56;
    const float4 v = *(const float4*)(x + xbase + (size_t)(r * 56 + c) * 384 + seg * 4);
    short4v o;
    o.x = f2bf(v.x); o.y = f2bf(v.y); o.z = f2bf(v.z); o.w = f2bf(v.w);
    *(short4v*)(&xs[tok * XS_STR + seg * 4]) = o;
  }
  __syncthreads();

  // ---------------- Phase 2: QKV GEMM (49x384 @ 384x1152) ----------------
  // 24 groups of (4 m-tiles x 3 n-tiles); wave w takes groups w, w+8, w+16
#pragma unroll
  for (int gg = 0; gg < 3; ++gg) {
    const int n0 = (wv + gg * 8) * 48;
    f32x4 acc[4][3];
#pragma unroll
    for (int m = 0; m < 4; ++m)
#pragma unroll
      for (int n = 0; n < 3; ++n) acc[m][n] = zf;

    for (int k = 0; k < 12; ++k) {
      const int kk = k * 32 + lhi * 8;
      short8 a[4];
#pragma unroll
      for (int m = 0; m < 4; ++m) {
        int row = m * 16 + l15;
        int rc = row < 49 ? row : 0;
        short8 v = *(const short8*)(&xs[rc * XS_STR + kk]);
        a[m] = (row < 49) ? v : zero8;
      }
#pragma unroll
      for (int n = 0; n < 3; ++n) {
        const short8 b = *(const short8*)(&wqkvT[(n0 + n * 16 + l15) * 384 + kk]);
#pragma unroll
        for (int m = 0; m < 4; ++m) acc[m][n] = MFMA(a[m], b, acc[m][n]);
      }
    }
    // epilogue: bf16 into qkv LDS
#pragma unroll
    for (int m = 0; m < 4; ++m)
#pragma unroll
      for (int n = 0; n < 3; ++n)
#pragma unroll
        for (int r = 0; r < 4; ++r) {
          int row = m * 16 + lhi * 4 + r;   // D: col=lane&15, row=(lane>>4)*4+reg
          if (row < 49) qkv[row * QK_STR + n0 + n * 16 + l15] = f2bf(acc[m][n][r]);
        }
  }
  __syncthreads();

  // ---------------- Phase 3: windowed attention ----------------
  // 24 tasks = 12 heads x 2 row-halves(32 rows); wave w takes w, w+8, w+16
  f32x4 O[3][2][2];
  short* Pbuf = &xs[wv * 2304];  // wave-private 32 x P_STR scratch (aliases xs)

#pragma unroll
  for (int tc = 0; tc < 3; ++tc) {
    const int task = wv + tc * 8;
    const int h = task >> 1;
    const int mh = task & 1;

    // Q fragments (A): rows mh*32+mi*16+l15, k = head feature
    short8 qa[2];
#pragma unroll
    for (int mi = 0; mi < 2; ++mi) {
      int row = mh * 32 + mi * 16 + l15;
      int rc = row < 49 ? row : 0;
      short8 v = *(const short8*)(&qkv[rc * QK_STR + h * 32 + lhi * 8]);
      qa[mi] = (row < 49) ? v : zero8;
    }
    // S = Q K^T
    f32x4 s[2][4];
#pragma unroll
    for (int nt = 0; nt < 4; ++nt) {
      int jr = nt * 16 + l15;
      int jc = jr < 49 ? jr : 0;
      short8 kb = *(const short8*)(&qkv[jc * QK_STR + 384 + h * 32 + lhi * 8]);
      kb = (jr < 49) ? kb : zero8;
#pragma unroll
      for (int mi = 0; mi < 2; ++mi) s[mi][nt] = MFMA(qa[mi], kb, zf);
    }

    // scale + relative-position bias + shift masks
#pragma unroll
    for (int mi = 0; mi < 2; ++mi)
#pragma unroll
      for (int r = 0; r < 4; ++r) {
        const int i = mh * 32 + mi * 16 + lhi * 4 + r;
        const int ai = (i * 37) >> 8, bi2 = i - ai * 7;
#pragma unroll
        for (int nt = 0; nt < 4; ++nt) {
          const int j = nt * 16 + l15;
          float v = s[mi][nt][r] * 0.17677669529663687f;
          if (i < 49 && j < 49) {
            int aj = (j * 37) >> 8, bj = j - aj * 7;
            v += pe[(aj - ai + 6) * 13 + (bj - bi2 + 6)];
            if (wy == 7 && ((i >= 28) != (j >= 28))) v = -1e30f;
            if (wx == 7 && ((bi2 >= 4) != (bj >= 4))) v = -1e30f;
          } else {
            v = -1e30f;   // padded columns/rows
          }
          s[mi][nt][r] = v;
        }
      }

    // softmax per row (cols spread over nt and lanes 0..15 of each 16-group)
#pragma unroll
    for (int mi = 0; mi < 2; ++mi)
#pragma unroll
      for (int r = 0; r < 4; ++r) {
        float mx = fmaxf(fmaxf(s[mi][0][r], s[mi][1][r]),
                         fmaxf(s[mi][2][r], s[mi][3][r]));
        mx = fmaxf(mx, __shfl_xor(mx, 1));
        mx = fmaxf(mx, __shfl_xor(mx, 2));
        mx = fmaxf(mx, __shfl_xor(mx, 4));
        mx = fmaxf(mx, __shfl_xor(mx, 8));
        float p0 = __expf(s[mi][0][r] - mx);
        float p1 = __expf(s[mi][1][r] - mx);
        float p2 = __expf(s[mi][2][r] - mx);
        float p3 = __expf(s[mi][3][r] - mx);
        float sum = p0 + p1 + p2 + p3;
        sum += __shfl_xor(sum, 1);
        sum += __shfl_xor(sum, 2);
        sum += __shfl_xor(sum, 4);
        sum += __shfl_xor(sum, 8);
        const float inv = 1.0f / sum;
        const int rowl = mi * 16 + lhi * 4 + r;
        Pbuf[rowl * P_STR +  0 + l15] = f2bf(p0 * inv);
        Pbuf[rowl * P_STR + 16 + l15] = f2bf(p1 * inv);
        Pbuf[rowl * P_STR + 32 + l15] = f2bf(p2 * inv);
        Pbuf[rowl * P_STR + 48 + l15] = f2bf(p3 * inv);
      }

    // O = P V
#pragma unroll
    for (int mi = 0; mi < 2; ++mi)
#pragma unroll
      for (int n2 = 0; n2 < 2; ++n2) O[tc][mi][n2] = zf;

#pragma unroll
    for (int ks = 0; ks < 2; ++ks) {
      short8 pa[2];
#pragma unroll
      for (int mi = 0; mi < 2; ++mi)
        pa[mi] = *(const short8*)(&Pbuf[(mi * 16 + l15) * P_STR + ks * 32 + lhi * 8]);
#pragma unroll
      for (int n2 = 0; n2 < 2; ++n2) {
        const int d = n2 * 16 + l15;
        short8 vb;
#pragma unroll
        for (int e = 0; e < 8; ++e) {
          int j = ks * 32 + lhi * 8 + e;
          vb[e] = (j < 49) ? qkv[j * QK_STR + 768 + h * 32 + d] : (short)0;
        }
#pragma unroll
        for (int mi = 0; mi < 2; ++mi) O[tc][mi][n2] = MFMA(pa[mi], vb, O[tc][mi][n2]);
      }
    }
  }
  __syncthreads();

  // store attn-out (bf16) into qkv region (Q/K/V dead now)
#pragma unroll
  for (int tc = 0; tc < 3; ++tc) {
    const int task = wv + tc * 8;
    const int h = task >> 1, mh = task & 1;
#pragma unroll
    for (int mi = 0; mi < 2; ++mi)
#pragma unroll
      for (int n2 = 0; n2 < 2; ++n2)
#pragma unroll
        for (int r = 0; r < 4; ++r) {
          int row = mh * 32 + mi * 16 + lhi * 4 + r;
          if (row < 49)
            qkv[row * AO_STR + h * 32 + n2 * 16 + l15] = f2bf(O[tc][mi][n2][r]);
        }
  }
  __syncthreads();

  // ---------------- Phase 4: out-proj (49x384 @ 384x384) + bias + inverse roll ----
  {
    const int n0 = wv * 48;   // 8 waves x (4m x 3n tiles) covers 64x384
    f32x4 acc[4][3];
#pragma unroll
    for (int m = 0; m < 4; ++m)
#pragma unroll
      for (int n = 0; n < 3; ++n) acc[m][n] = zf;

    for (int k = 0; k < 12; ++k) {
      const int kk = k * 32 + lhi * 8;
      short8 a[4];
#pragma unroll
      for (int m = 0; m < 4; ++m) {
        int row = m * 16 + l15;
        int rc = row < 49 ? row : 0;
        short8 v = *(const short8*)(&qkv[rc * AO_STR + kk]);
        a[m] = (row < 49) ? v : zero8;
      }
#pragma unroll
      for (int n = 0; n < 3; ++n) {
        const short8 b = *(const short8*)(&woutT[(n0 + n * 16 + l15) * 384 + kk]);
#pragma unroll
        for (int m = 0; m < 4; ++m) acc[m][n] = MFMA(a[m], b, acc[m][n]);
      }
    }

    float bo[3];
#pragma unroll
    for (int n = 0; n < 3; ++n) bo[n] = bout[n0 + n * 16 + l15];

#pragma unroll
    for (int m = 0; m < 4; ++m)
#pragma unroll
      for (int r = 0; r < 4; ++r) {
        const int row = m * 16 + lhi * 4 + r;
        if (row < 49) {
          int iy = (row * 37) >> 8, ix = row - iy * 7;
          int rr = wy * 7 + iy + 3; if (rr >= 56) rr -= 56;
          int cc = wx * 7 + ix + 3; if (cc >= 56) cc -= 56;
          float* dst = out + xbase + (size_t)(rr * 56 + cc) * 384 + n0;
#pragma unroll
          for (int n = 0; n < 3; ++n) dst[n * 16 + l15] = acc[m][n][r] + bo[n];
        }
      }
  }
}

extern "C" void kernel_launch(void* const* d_in, const int* in_sizes, int n_in,
                              void* d_out, int out_size, void* d_ws, size_t ws_size,
                              hipStream_t stream) {
  const float* x    = (const float*)d_in[0];
  const float* wqkv = (const float*)d_in[1];
  const float* pos  = (const float*)d_in[2];
  const float* wout = (const float*)d_in[3];
  const float* bo   = (const float*)d_in[4];

  short* wqkvT = (short*)d_ws;                              // [1152][384] bf16
  short* woutT = (short*)((char*)d_ws + 1152 * 384 * 2);    // [384][384] bf16

  prep_weights<<<1728, 256, 0, stream>>>(wqkv, wout, wqkvT, woutT);
  swin_fused<<<2048, 512, 0, stream>>>(x, wqkvT, pos, woutT, bo, (float*)d_out);
}

// Round 2
// 459.575 us; speedup vs baseline: 1.0215x; 1.0215x over previous
//
#include <hip/hip_runtime.h>

typedef __attribute__((ext_vector_type(8))) short short8;
typedef __attribute__((ext_vector_type(4))) short short4v;
typedef __attribute__((ext_vector_type(4))) float f32x4;

#define MFMA(a, b, c) __builtin_amdgcn_mfma_f32_16x16x32_bf16(a, b, c, 0, 0, 0)

__device__ __forceinline__ short f2bf(float f) {
  union { float f; unsigned u; } v;
  v.f = f;
  unsigned r = v.u + 0x7fffu + ((v.u >> 16) & 1u);
  return (short)(r >> 16);
}

// strides in shorts: byte stride %16==0 (b128 align), dword stride %32==4 -> 2-way alias (free, m136)
#define XS_STR  392   // x window stride (384+8)
#define QKG_STR 392   // per-group qkv stride (384+8)
#define AO_STR  392
#define P_STR   72    // P scratch stride (64+8)

__global__ void prep_weights(const float* __restrict__ wqkv,
                             const float* __restrict__ wout,
                             short* __restrict__ wqkvT,
                             short* __restrict__ woutT) {
  int i = blockIdx.x * 256 + threadIdx.x;
  if (i < 1152 * 384) {                  // wqkvT[n][k] = wqkv[k][n]
    int n = i / 384, k = i - (i / 384) * 384;
    wqkvT[i] = f2bf(wqkv[k * 1152 + n]);
  }
  if (i < 384 * 384) {                   // woutT[n][k] = wout[k][n]
    int n = i / 384, k = i - (i / 384) * 384;
    woutT[i] = f2bf(wout[k * 384 + n]);
  }
}

// ---------------- K1: QKV GEMM (4-head slice) + windowed attention ----------------
__global__ __launch_bounds__(512, 4) void swin_qkv_attn(
    const float* __restrict__ x, const short* __restrict__ wqkvT,
    const float* __restrict__ pos_emb, short* __restrict__ aout) {

  __shared__ short xs[49 * XS_STR];    // 38,416 B; aliased by Pbuf in phase 3
  __shared__ short qkv[49 * QKG_STR];  // 38,416 B: cols 0..127 Q(h0..3) | 128..255 K | 256..383 V
  __shared__ float pe[169];

  const int tid = threadIdx.x;
  const int lane = tid & 63;
  const int wv = tid >> 6;
  const int l15 = lane & 15;
  const int lhi = lane >> 4;

  // XCD-chunked bijective swizzle (6144 % 8 == 0): each XCD gets contiguous (window,g) triples
  const int bid = blockIdx.x;
  const int sw = (bid & 7) * 768 + (bid >> 3);
  const int g = sw - (sw / 3) * 3;     // head-group 0..2 (fastest -> same XCD as siblings)
  const int bw = sw / 3;
  const int batch = bw >> 6;
  const int win = bw & 63;
  const int wy = win >> 3, wx = win & 7;

  if (tid < 169) pe[tid] = pos_emb[tid];

  const size_t xbase = (size_t)batch * (56 * 56 * 384);
  const short8 zero8 = {0, 0, 0, 0, 0, 0, 0, 0};
  const f32x4 zf = {0.f, 0.f, 0.f, 0.f};

  // Phase 1: load shifted x window -> xs (bf16)
  for (int t = tid; t < 49 * 96; t += 512) {
    int tok = t / 96;
    int seg = t - tok * 96;
    int iy = (tok * 37) >> 8;
    int ix = tok - iy * 7;
    int r = wy * 7 + iy + 3; if (r >= 56) r -= 56;
    int c = wx * 7 + ix + 3; if (c >= 56) c -= 56;
    const float4 v = *(const float4*)(x + xbase + (size_t)(r * 56 + c) * 384 + seg * 4);
    short4v o;
    o.x = f2bf(v.x); o.y = f2bf(v.y); o.z = f2bf(v.z); o.w = f2bf(v.w);
    *(short4v*)(&xs[tok * XS_STR + seg * 4]) = o;
  }
  __syncthreads();

  // Phase 2: QKV GEMM for head group g: 49x384 @ 384x384 (cols = q/k/v of heads 4g..4g+3)
  {
    const int n0 = wv * 48;
    int wrow[3];
#pragma unroll
    for (int n = 0; n < 3; ++n) {
      const int c0 = n0 + n * 16;
      const int seg = c0 >> 7;             // 0=q 1=k 2=v
      const int hl = (c0 >> 5) & 3;        // head within group
      wrow[n] = seg * 384 + (g * 4 + hl) * 32 + (c0 & 31);
    }
    f32x4 acc[4][3];
#pragma unroll
    for (int m = 0; m < 4; ++m)
#pragma unroll
      for (int n = 0; n < 3; ++n) acc[m][n] = zf;

    for (int k = 0; k < 12; ++k) {
      const int kk = k * 32 + lhi * 8;
      short8 a[4];
#pragma unroll
      for (int m = 0; m < 4; ++m) {
        int row = m * 16 + l15;
        int rc = row < 49 ? row : 0;
        short8 v = *(const short8*)(&xs[rc * XS_STR + kk]);
        a[m] = (row < 49) ? v : zero8;
      }
#pragma unroll
      for (int n = 0; n < 3; ++n) {
        const short8 b = *(const short8*)(&wqkvT[(wrow[n] + l15) * 384 + kk]);
#pragma unroll
        for (int m = 0; m < 4; ++m) acc[m][n] = MFMA(a[m], b, acc[m][n]);
      }
    }
#pragma unroll
    for (int m = 0; m < 4; ++m)
#pragma unroll
      for (int n = 0; n < 3; ++n)
#pragma unroll
        for (int r = 0; r < 4; ++r) {
          int row = m * 16 + lhi * 4 + r;
          if (row < 49) qkv[row * QKG_STR + n0 + n * 16 + l15] = f2bf(acc[m][n][r]);
        }
  }
  __syncthreads();

  // Phase 3: attention — one task per wave: head hl = wv>>1, row-half mh = wv&1
  {
    const int hl = wv >> 1;
    const int mh = wv & 1;
    short* Pbuf = &xs[wv * 2304];   // wave-private 32 x P_STR (xs dead after phase 2)

    short8 qa[2];
#pragma unroll
    for (int mi = 0; mi < 2; ++mi) {
      int row = mh * 32 + mi * 16 + l15;
      int rc = row < 49 ? row : 0;
      short8 v = *(const short8*)(&qkv[rc * QKG_STR + hl * 32 + lhi * 8]);
      qa[mi] = (row < 49) ? v : zero8;
    }
    f32x4 s[2][4];
#pragma unroll
    for (int nt = 0; nt < 4; ++nt) {
      int jr = nt * 16 + l15;
      int jc = jr < 49 ? jr : 0;
      short8 kb = *(const short8*)(&qkv[jc * QKG_STR + 128 + hl * 32 + lhi * 8]);
      kb = (jr < 49) ? kb : zero8;
#pragma unroll
      for (int mi = 0; mi < 2; ++mi) s[mi][nt] = MFMA(qa[mi], kb, zf);
    }

#pragma unroll
    for (int mi = 0; mi < 2; ++mi)
#pragma unroll
      for (int r = 0; r < 4; ++r) {
        const int i = mh * 32 + mi * 16 + lhi * 4 + r;
        const int ai = (i * 37) >> 8, bi2 = i - ai * 7;
#pragma unroll
        for (int nt = 0; nt < 4; ++nt) {
          const int j = nt * 16 + l15;
          float v = s[mi][nt][r] * 0.17677669529663687f;
          if (i < 49 && j < 49) {
            int aj = (j * 37) >> 8, bj = j - aj * 7;
            v += pe[(aj - ai + 6) * 13 + (bj - bi2 + 6)];
            if (wy == 7 && ((i >= 28) != (j >= 28))) v = -1e30f;
            if (wx == 7 && ((bi2 >= 4) != (bj >= 4))) v = -1e30f;
          } else {
            v = -1e30f;
          }
          s[mi][nt][r] = v;
        }
      }

#pragma unroll
    for (int mi = 0; mi < 2; ++mi)
#pragma unroll
      for (int r = 0; r < 4; ++r) {
        float mx = fmaxf(fmaxf(s[mi][0][r], s[mi][1][r]),
                         fmaxf(s[mi][2][r], s[mi][3][r]));
        mx = fmaxf(mx, __shfl_xor(mx, 1));
        mx = fmaxf(mx, __shfl_xor(mx, 2));
        mx = fmaxf(mx, __shfl_xor(mx, 4));
        mx = fmaxf(mx, __shfl_xor(mx, 8));
        float p0 = __expf(s[mi][0][r] - mx);
        float p1 = __expf(s[mi][1][r] - mx);
        float p2 = __expf(s[mi][2][r] - mx);
        float p3 = __expf(s[mi][3][r] - mx);
        float sum = p0 + p1 + p2 + p3;
        sum += __shfl_xor(sum, 1);
        sum += __shfl_xor(sum, 2);
        sum += __shfl_xor(sum, 4);
        sum += __shfl_xor(sum, 8);
        const float inv = 1.0f / sum;
        const int rowl = mi * 16 + lhi * 4 + r;
        Pbuf[rowl * P_STR +  0 + l15] = f2bf(p0 * inv);
        Pbuf[rowl * P_STR + 16 + l15] = f2bf(p1 * inv);
        Pbuf[rowl * P_STR + 32 + l15] = f2bf(p2 * inv);
        Pbuf[rowl * P_STR + 48 + l15] = f2bf(p3 * inv);
      }

    f32x4 O[2][2];
#pragma unroll
    for (int mi = 0; mi < 2; ++mi)
#pragma unroll
      for (int n2 = 0; n2 < 2; ++n2) O[mi][n2] = zf;

#pragma unroll
    for (int ks = 0; ks < 2; ++ks) {
      short8 pa[2];
#pragma unroll
      for (int mi = 0; mi < 2; ++mi)
        pa[mi] = *(const short8*)(&Pbuf[(mi * 16 + l15) * P_STR + ks * 32 + lhi * 8]);
#pragma unroll
      for (int n2 = 0; n2 < 2; ++n2) {
        const int d = n2 * 16 + l15;
        short8 vb;
#pragma unroll
        for (int e = 0; e < 8; ++e) {
          int j = ks * 32 + lhi * 8 + e;
          vb[e] = (j < 49) ? qkv[j * QKG_STR + 256 + hl * 32 + d] : (short)0;
        }
#pragma unroll
        for (int mi = 0; mi < 2; ++mi) O[mi][n2] = MFMA(pa[mi], vb, O[mi][n2]);
      }
    }

    // write attn-out (bf16) to global: [win][tok][inner], inner col = (4g+hl)*32 + d
    short* ab = aout + (size_t)bw * (49 * 384) + (g * 4 + hl) * 32;
#pragma unroll
    for (int mi = 0; mi < 2; ++mi)
#pragma unroll
      for (int n2 = 0; n2 < 2; ++n2)
#pragma unroll
        for (int r = 0; r < 4; ++r) {
          int row = mh * 32 + mi * 16 + lhi * 4 + r;
          if (row < 49) ab[row * 384 + n2 * 16 + l15] = f2bf(O[mi][n2][r]);
        }
  }
}

// ---------------- K2: out-proj (49x384 @ 384x384) + bias + inverse roll ----------------
__global__ __launch_bounds__(512, 4) void swin_outproj(
    const short* __restrict__ aout, const short* __restrict__ woutT,
    const float* __restrict__ bout, float* __restrict__ out) {

  __shared__ short ao[49 * AO_STR];   // 38,416 B

  const int tid = threadIdx.x;
  const int lane = tid & 63;
  const int wv = tid >> 6;
  const int l15 = lane & 15;
  const int lhi = lane >> 4;

  const int bw = blockIdx.x;
  const int batch = bw >> 6;
  const int win = bw & 63;
  const int wy = win >> 3, wx = win & 7;

  const size_t xbase = (size_t)batch * (56 * 56 * 384);
  const short8 zero8 = {0, 0, 0, 0, 0, 0, 0, 0};
  const f32x4 zf = {0.f, 0.f, 0.f, 0.f};

  // load attn-out window -> LDS
  const short* ab = aout + (size_t)bw * (49 * 384);
  for (int t = tid; t < 49 * 48; t += 512) {
    int row = t / 48;
    int seg = t - row * 48;
    *(short8*)(&ao[row * AO_STR + seg * 8]) = *(const short8*)(&ab[row * 384 + seg * 8]);
  }
  __syncthreads();

  {
    const int n0 = wv * 48;
    f32x4 acc[4][3];
#pragma unroll
    for (int m = 0; m < 4; ++m)
#pragma unroll
      for (int n = 0; n < 3; ++n) acc[m][n] = zf;

    for (int k = 0; k < 12; ++k) {
      const int kk = k * 32 + lhi * 8;
      short8 a[4];
#pragma unroll
      for (int m = 0; m < 4; ++m) {
        int row = m * 16 + l15;
        int rc = row < 49 ? row : 0;
        short8 v = *(const short8*)(&ao[rc * AO_STR + kk]);
        a[m] = (row < 49) ? v : zero8;
      }
#pragma unroll
      for (int n = 0; n < 3; ++n) {
        const short8 b = *(const short8*)(&woutT[(n0 + n * 16 + l15) * 384 + kk]);
#pragma unroll
        for (int m = 0; m < 4; ++m) acc[m][n] = MFMA(a[m], b, acc[m][n]);
      }
    }

    float bo[3];
#pragma unroll
    for (int n = 0; n < 3; ++n) bo[n] = bout[n0 + n * 16 + l15];

#pragma unroll
    for (int m = 0; m < 4; ++m)
#pragma unroll
      for (int r = 0; r < 4; ++r) {
        const int row = m * 16 + lhi * 4 + r;
        if (row < 49) {
          int iy = (row * 37) >> 8, ix = row - iy * 7;
          int rr = wy * 7 + iy + 3; if (rr >= 56) rr -= 56;
          int cc = wx * 7 + ix + 3; if (cc >= 56) cc -= 56;
          float* dst = out + xbase + (size_t)(rr * 56 + cc) * 384 + n0;
#pragma unroll
          for (int n = 0; n < 3; ++n) dst[n * 16 + l15] = acc[m][n][r] + bo[n];
        }
      }
  }
}

extern "C" void kernel_launch(void* const* d_in, const int* in_sizes, int n_in,
                              void* d_out, int out_size, void* d_ws, size_t ws_size,
                              hipStream_t stream) {
  const float* x    = (const float*)d_in[0];
  const float* wqkv = (const float*)d_in[1];
  const float* pos  = (const float*)d_in[2];
  const float* wout = (const float*)d_in[3];
  const float* bo   = (const float*)d_in[4];

  short* wqkvT = (short*)d_ws;                              // [1152][384] bf16
  short* woutT = (short*)((char*)d_ws + 1152 * 384 * 2);    // [384][384] bf16
  short* aoutg = (short*)((char*)d_ws + (1152 + 384) * 384 * 2);  // [2048][49][384] bf16 (~77 MB)

  prep_weights<<<1728, 256, 0, stream>>>(wqkv, wout, wqkvT, woutT);
  swin_qkv_attn<<<6144, 512, 0, stream>>>(x, wqkvT, pos, aoutg);
  swin_outproj<<<2048, 512, 0, stream>>>(aoutg, woutT, bo, (float*)d_out);
}

// Round 5
// 408.241 us; speedup vs baseline: 1.1499x; 1.1257x over previous
//
#include <hip/hip_runtime.h>

typedef __attribute__((ext_vector_type(8))) short short8;
typedef __attribute__((ext_vector_type(4))) short short4v;
typedef __attribute__((ext_vector_type(4))) float f32x4;
typedef __attribute__((ext_vector_type(2))) int int2v;

#define MFMA(a, b, c) __builtin_amdgcn_mfma_f32_16x16x32_bf16(a, b, c, 0, 0, 0)
#define SCALE 0.17677669529663687f

__device__ __forceinline__ short f2bf(float f) {
  union { float f; unsigned u; } v;
  v.f = f;
  unsigned r = v.u + 0x7fffu + ((v.u >> 16) & 1u);
  return (short)(r >> 16);
}

__device__ __forceinline__ unsigned cvt_pk(float lo, float hi) {
  unsigned r;
  asm("v_cvt_pk_bf16_f32 %0, %1, %2" : "=v"(r) : "v"(lo), "v"(hi));
  return r;
}

// strides in shorts: byte stride %16==0 (b128 align), dword stride %32==4 -> 2-way alias (free)
#define XS_STR 392   // x window stride (384+8)
#define QK_STR 264   // Q|K stride (256+8)
#define P_STR  72    // P scratch stride (64+8)
#define AO_STR 392

__global__ void prep_weights(const float* __restrict__ wqkv,
                             const float* __restrict__ wout,
                             short* __restrict__ wqkvT,
                             short* __restrict__ woutT) {
  int i = blockIdx.x * 256 + threadIdx.x;
  if (i < 1152 * 384) {                  // wqkvT[n][k] = wqkv[k][n]
    int n = i / 384, k = i - (i / 384) * 384;
    wqkvT[i] = f2bf(wqkv[k * 1152 + n]);
  }
  if (i < 384 * 384) {                   // woutT[n][k] = wout[k][n]
    int n = i / 384, k = i - (i / 384) * 384;
    woutT[i] = f2bf(wout[k * 384 + n]);
  }
}

// bias table: btabT[t][i][c][nt] = bias(i, j=nt*16+c) for window-type t
// t = (wy==7 ? 1 : 0) | (wx==7 ? 2 : 0); includes pos-emb, shift masks, j>=49 kill
__global__ void prep_bias(const float* __restrict__ pe, float* __restrict__ btabT) {
  int id = blockIdx.x * 256 + threadIdx.x;   // 4*64*64
  if (id >= 16384) return;
  int t = id >> 12;
  int i = (id >> 6) & 63;
  int j = id & 63;
  float v;
  if (i < 49 && j < 49) {
    int ai = i / 7, bi = i - ai * 7, aj = j / 7, bj = j - aj * 7;
    v = pe[(aj - ai + 6) * 13 + (bj - bi + 6)];
    if ((t & 1) && ((i >= 28) != (j >= 28))) v = -1e30f;
    if ((t & 2) && ((bi >= 4) != (bj >= 4))) v = -1e30f;
  } else if (j < 49) {
    v = 0.f;
  } else {
    v = -1e30f;
  }
  btabT[((t * 64 + i) * 16 + (j & 15)) * 4 + (j >> 4)] = v;
}

// ---------------- K1: QKV GEMM (4-head slice) + windowed attention ----------------
__global__ __launch_bounds__(512, 4) void swin_qkv_attn(
    const float* __restrict__ x, const short* __restrict__ wqkvT,
    const float* __restrict__ btabT, short* __restrict__ aout) {

  __shared__ short xs[49 * XS_STR];   // 38,416 B; aliased by Pbuf in phase 3
  __shared__ short qk[49 * QK_STR];   // 25,872 B: cols 0..127 Q | 128..255 K
  __shared__ short vT[128 * 64];      // 16,384 B: vT[d][j], byte ^= (d&7)<<4 swizzle

  const int tid = threadIdx.x;
  const int lane = tid & 63;
  const int wv = tid >> 6;
  const int l15 = lane & 15;
  const int lhi = lane >> 4;

  // XCD-chunked bijective swizzle (6144 % 8 == 0)
  const int bid = blockIdx.x;
  const int sw = (bid & 7) * 768 + (bid >> 3);
  const int g = sw - (sw / 3) * 3;
  const int bw = sw / 3;
  const int batch = bw >> 6;
  const int win = bw & 63;
  const int wy = win >> 3, wx = win & 7;

  const size_t xbase = (size_t)batch * (56 * 56 * 384);
  const f32x4 zf = {0.f, 0.f, 0.f, 0.f};

  // zero vT (covers garbage rows j>=49; swizzle is bijective so linear zero is fine)
  {
    int* vz = (int*)vT;
    for (int t2 = tid; t2 < 4096; t2 += 512) vz[t2] = 0;
  }

  // Phase 1: load shifted x window -> xs (bf16 via cvt_pk)
  for (int t = tid; t < 49 * 96; t += 512) {
    int tok = t / 96;
    int seg = t - tok * 96;
    int iy = (tok * 37) >> 8;
    int ix = tok - iy * 7;
    int r = wy * 7 + iy + 3; if (r >= 56) r -= 56;
    int c = wx * 7 + ix + 3; if (c >= 56) c -= 56;
    const float4 v = *(const float4*)(x + xbase + (size_t)(r * 56 + c) * 384 + seg * 4);
    int2v o;
    o.x = (int)cvt_pk(v.x, v.y);
    o.y = (int)cvt_pk(v.z, v.w);
    *(int2v*)(&xs[tok * XS_STR + seg * 4]) = o;
  }
  __syncthreads();

  // Phase 2: QKV GEMM for head group g: 49x384 @ 384x384
  {
    const int n0 = wv * 48;
    const short* pB[3];
#pragma unroll
    for (int n = 0; n < 3; ++n) {
      const int c0 = n0 + n * 16;
      const int seg = c0 >> 7;             // 0=q 1=k 2=v
      const int hloc = (c0 >> 5) & 3;
      const int wrow = seg * 384 + (g * 4 + hloc) * 32 + (c0 & 31);
      pB[n] = wqkvT + (size_t)(wrow + l15) * 384 + lhi * 8;
    }
    f32x4 acc[4][3];
#pragma unroll
    for (int m = 0; m < 4; ++m)
#pragma unroll
      for (int n = 0; n < 3; ++n) acc[m][n] = zf;

    const short* pA[4];
#pragma unroll
    for (int m = 0; m < 4; ++m) {
      int row = m * 16 + l15;
      int rc = row < 49 ? row : 48;        // clamp: garbage C rows >=49 never stored
      pA[m] = &xs[rc * XS_STR + lhi * 8];
    }

    short8 bc[3];
#pragma unroll
    for (int n = 0; n < 3; ++n) bc[n] = *(const short8*)(pB[n]);

#pragma unroll
    for (int k = 0; k < 12; ++k) {
      short8 bn[3];
      const int kn = (k < 11) ? (k + 1) * 32 : 11 * 32;
#pragma unroll
      for (int n = 0; n < 3; ++n) bn[n] = *(const short8*)(pB[n] + kn);
      short8 a[4];
#pragma unroll
      for (int m = 0; m < 4; ++m) a[m] = *(const short8*)(pA[m] + k * 32);
#pragma unroll
      for (int n = 0; n < 3; ++n)
#pragma unroll
        for (int m = 0; m < 4; ++m) acc[m][n] = MFMA(a[m], bc[n], acc[m][n]);
#pragma unroll
      for (int n = 0; n < 3; ++n) bc[n] = bn[n];
    }

    // epilogue: Q (scaled) and K -> qk, V -> vT (transposed + swizzled)
#pragma unroll
    for (int n = 0; n < 3; ++n) {
      const int c0 = n0 + n * 16;
#pragma unroll
      for (int m = 0; m < 4; ++m)
#pragma unroll
        for (int r = 0; r < 4; ++r) {
          int row = m * 16 + lhi * 4 + r;
          if (row < 49) {
            if (c0 < 128) {
              qk[row * QK_STR + c0 + l15] = f2bf(acc[m][n][r] * SCALE);
            } else if (c0 < 256) {
              qk[row * QK_STR + c0 + l15] = f2bf(acc[m][n][r]);
            } else {
              const int d = c0 - 256 + l15;
              *(short*)((char*)vT + d * 128 + ((2 * row) ^ ((d & 7) << 4))) =
                  f2bf(acc[m][n][r]);
            }
          }
        }
    }
  }
  __syncthreads();

  // Phase 3: attention — one task per wave: head hl = wv>>1, row-half mh = wv&1
  {
    const int hl = wv >> 1;
    const int mh = wv & 1;
    const int tt = (wy == 7 ? 1 : 0) | (wx == 7 ? 2 : 0);
    short* Pbuf = &xs[wv * 2304];   // wave-private 32 x P_STR (xs dead)

    // bias loads (independent of S — issue early)
    f32x4 bb[2][4];
#pragma unroll
    for (int mi = 0; mi < 2; ++mi)
#pragma unroll
      for (int r = 0; r < 4; ++r) {
        const int i = mh * 32 + mi * 16 + lhi * 4 + r;
        bb[mi][r] = *(const f32x4*)(&btabT[((tt * 64 + i) * 16 + l15) * 4]);
      }

    short8 qa[2];
#pragma unroll
    for (int mi = 0; mi < 2; ++mi) {
      int row = mh * 32 + mi * 16 + l15;
      int rc = row < 49 ? row : 48;
      qa[mi] = *(const short8*)(&qk[rc * QK_STR + hl * 32 + lhi * 8]);
    }
    f32x4 s[2][4];
#pragma unroll
    for (int nt = 0; nt < 4; ++nt) {
      int jr = nt * 16 + l15;
      int jc = jr < 49 ? jr : 48;          // garbage cols killed by bias -1e30
      short8 kb = *(const short8*)(&qk[jc * QK_STR + 128 + hl * 32 + lhi * 8]);
#pragma unroll
      for (int mi = 0; mi < 2; ++mi) s[mi][nt] = MFMA(qa[mi], kb, zf);
    }

    // bias add (scale already folded into Q)
#pragma unroll
    for (int mi = 0; mi < 2; ++mi)
#pragma unroll
      for (int r = 0; r < 4; ++r)
#pragma unroll
        for (int nt = 0; nt < 4; ++nt)
          s[mi][nt][r] += bb[mi][r][nt];

    // softmax per row
#pragma unroll
    for (int mi = 0; mi < 2; ++mi)
#pragma unroll
      for (int r = 0; r < 4; ++r) {
        float mx = fmaxf(fmaxf(s[mi][0][r], s[mi][1][r]),
                         fmaxf(s[mi][2][r], s[mi][3][r]));
        mx = fmaxf(mx, __shfl_xor(mx, 1));
        mx = fmaxf(mx, __shfl_xor(mx, 2));
        mx = fmaxf(mx, __shfl_xor(mx, 4));
        mx = fmaxf(mx, __shfl_xor(mx, 8));
        float p0 = __expf(s[mi][0][r] - mx);
        float p1 = __expf(s[mi][1][r] - mx);
        float p2 = __expf(s[mi][2][r] - mx);
        float p3 = __expf(s[mi][3][r] - mx);
        float sum = p0 + p1 + p2 + p3;
        sum += __shfl_xor(sum, 1);
        sum += __shfl_xor(sum, 2);
        sum += __shfl_xor(sum, 4);
        sum += __shfl_xor(sum, 8);
        const float inv = __builtin_amdgcn_rcpf(sum);
        const int rowl = mi * 16 + lhi * 4 + r;
        Pbuf[rowl * P_STR +  0 + l15] = f2bf(p0 * inv);
        Pbuf[rowl * P_STR + 16 + l15] = f2bf(p1 * inv);
        Pbuf[rowl * P_STR + 32 + l15] = f2bf(p2 * inv);
        Pbuf[rowl * P_STR + 48 + l15] = f2bf(p3 * inv);
      }

    f32x4 O[2][2];
#pragma unroll
    for (int mi = 0; mi < 2; ++mi)
#pragma unroll
      for (int n2 = 0; n2 < 2; ++n2) O[mi][n2] = zf;

#pragma unroll
    for (int ks = 0; ks < 2; ++ks) {
      short8 pa[2];
#pragma unroll
      for (int mi = 0; mi < 2; ++mi)
        pa[mi] = *(const short8*)(&Pbuf[(mi * 16 + l15) * P_STR + ks * 32 + lhi * 8]);
#pragma unroll
      for (int n2 = 0; n2 < 2; ++n2) {
        const int dg = hl * 32 + n2 * 16 + l15;   // FIX: head offset was missing
        const short8 vb = *(const short8*)((const char*)vT + dg * 128 +
                              ((ks * 64 + lhi * 16) ^ ((dg & 7) << 4)));
#pragma unroll
        for (int mi = 0; mi < 2; ++mi) O[mi][n2] = MFMA(pa[mi], vb, O[mi][n2]);
      }
    }

    short* ab = aout + (size_t)bw * (49 * 384) + (g * 4 + hl) * 32;
#pragma unroll
    for (int mi = 0; mi < 2; ++mi)
#pragma unroll
      for (int n2 = 0; n2 < 2; ++n2)
#pragma unroll
        for (int r = 0; r < 4; ++r) {
          int row = mh * 32 + mi * 16 + lhi * 4 + r;
          if (row < 49) ab[row * 384 + n2 * 16 + l15] = f2bf(O[mi][n2][r]);
        }
  }
}

// ---------------- K2: out-proj (49x384 @ 384x384) + bias + inverse roll ----------------
__global__ __launch_bounds__(512, 4) void swin_outproj(
    const short* __restrict__ aout, const short* __restrict__ woutT,
    const float* __restrict__ bout, float* __restrict__ out) {

  __shared__ short ao[49 * AO_STR];   // 38,416 B

  const int tid = threadIdx.x;
  const int lane = tid & 63;
  const int wv = tid >> 6;
  const int l15 = lane & 15;
  const int lhi = lane >> 4;

  const int bw = blockIdx.x;
  const int batch = bw >> 6;
  const int win = bw & 63;
  const int wy = win >> 3, wx = win & 7;

  const size_t xbase = (size_t)batch * (56 * 56 * 384);
  const f32x4 zf = {0.f, 0.f, 0.f, 0.f};

  const short* abg = aout + (size_t)bw * (49 * 384);
  for (int t = tid; t < 49 * 48; t += 512) {
    int row = t / 48;
    int seg = t - row * 48;
    *(short8*)(&ao[row * AO_STR + seg * 8]) = *(const short8*)(&abg[row * 384 + seg * 8]);
  }
  __syncthreads();

  {
    const int n0 = wv * 48;
    f32x4 acc[4][3];
#pragma unroll
    for (int m = 0; m < 4; ++m)
#pragma unroll
      for (int n = 0; n < 3; ++n) acc[m][n] = zf;

    const short* pB[3];
#pragma unroll
    for (int n = 0; n < 3; ++n)
      pB[n] = woutT + (size_t)(n0 + n * 16 + l15) * 384 + lhi * 8;

    const short* pA[4];
#pragma unroll
    for (int m = 0; m < 4; ++m) {
      int row = m * 16 + l15;
      int rc = row < 49 ? row : 48;
      pA[m] = &ao[rc * AO_STR + lhi * 8];
    }

    short8 bc[3];
#pragma unroll
    for (int n = 0; n < 3; ++n) bc[n] = *(const short8*)(pB[n]);

#pragma unroll
    for (int k = 0; k < 12; ++k) {
      short8 bn[3];
      const int kn = (k < 11) ? (k + 1) * 32 : 11 * 32;
#pragma unroll
      for (int n = 0; n < 3; ++n) bn[n] = *(const short8*)(pB[n] + kn);
      short8 a[4];
#pragma unroll
      for (int m = 0; m < 4; ++m) a[m] = *(const short8*)(pA[m] + k * 32);
#pragma unroll
      for (int n = 0; n < 3; ++n)
#pragma unroll
        for (int m = 0; m < 4; ++m) acc[m][n] = MFMA(a[m], bc[n], acc[m][n]);
#pragma unroll
      for (int n = 0; n < 3; ++n) bc[n] = bn[n];
    }

    float bo[3];
#pragma unroll
    for (int n = 0; n < 3; ++n) bo[n] = bout[n0 + n * 16 + l15];

#pragma unroll
    for (int m = 0; m < 4; ++m)
#pragma unroll
      for (int r = 0; r < 4; ++r) {
        const int row = m * 16 + lhi * 4 + r;
        if (row < 49) {
          int iy = (row * 37) >> 8, ix = row - iy * 7;
          int rr = wy * 7 + iy + 3; if (rr >= 56) rr -= 56;
          int cc = wx * 7 + ix + 3; if (cc >= 56) cc -= 56;
          float* dst = out + xbase + (size_t)(rr * 56 + cc) * 384 + n0;
#pragma unroll
          for (int n = 0; n < 3; ++n) dst[n * 16 + l15] = acc[m][n][r] + bo[n];
        }
      }
  }
}

extern "C" void kernel_launch(void* const* d_in, const int* in_sizes, int n_in,
                              void* d_out, int out_size, void* d_ws, size_t ws_size,
                              hipStream_t stream) {
  const float* x    = (const float*)d_in[0];
  const float* wqkv = (const float*)d_in[1];
  const float* pos  = (const float*)d_in[2];
  const float* wout = (const float*)d_in[3];
  const float* bo   = (const float*)d_in[4];

  char* ws = (char*)d_ws;
  short* wqkvT = (short*)ws;                         ws += 1152 * 384 * 2;
  short* woutT = (short*)ws;                         ws += 384 * 384 * 2;
  float* btabT = (float*)ws;                         ws += 4 * 64 * 16 * 4 * 4;
  short* aoutg = (short*)ws;                         // [2048][49][384] bf16 (~77 MB)

  prep_weights<<<1728, 256, 0, stream>>>(wqkv, wout, wqkvT, woutT);
  prep_bias<<<64, 256, 0, stream>>>(pos, btabT);
  swin_qkv_attn<<<6144, 512, 0, stream>>>(x, wqkvT, btabT, aoutg);
  swin_outproj<<<2048, 512, 0, stream>>>(aoutg, woutT, bo, (float*)d_out);
}

// Round 6
// 401.556 us; speedup vs baseline: 1.1691x; 1.0166x over previous
//
#include <hip/hip_runtime.h>

typedef __attribute__((ext_vector_type(8))) short short8;
typedef __attribute__((ext_vector_type(4))) short short4v;
typedef __attribute__((ext_vector_type(4))) float f32x4;
typedef __attribute__((ext_vector_type(2))) int int2v;

#define MFMA(a, b, c) __builtin_amdgcn_mfma_f32_16x16x32_bf16(a, b, c, 0, 0, 0)
#define SCALE 0.17677669529663687f

__device__ __forceinline__ short f2bf(float f) {
  union { float f; unsigned u; } v;
  v.f = f;
  unsigned r = v.u + 0x7fffu + ((v.u >> 16) & 1u);
  return (short)(r >> 16);
}

__device__ __forceinline__ unsigned cvt_pk(float lo, float hi) {
  unsigned r;
  asm("v_cvt_pk_bf16_f32 %0, %1, %2" : "=v"(r) : "v"(lo), "v"(hi));
  return r;
}

// strides in shorts: byte stride %16==0 (b128 align), dword stride %32==4 -> 2-way alias (free)
#define XS_STR 392   // x window stride (384+8)
#define QK_STR 264   // Q|K stride (256+8)
#define P_STR  72    // P scratch stride (64+8)
#define AO_STR 392

__global__ void prep_weights(const float* __restrict__ wqkv,
                             const float* __restrict__ wout,
                             short* __restrict__ wqkvT,
                             short* __restrict__ woutT) {
  int i = blockIdx.x * 256 + threadIdx.x;
  if (i < 1152 * 384) {                  // wqkvT[n][k] = wqkv[k][n]; Q rows pre-scaled
    int n = i / 384, k = i - (i / 384) * 384;
    float w = wqkv[k * 1152 + n];
    if (n < 384) w *= SCALE;             // fold attn scale into Q weights
    wqkvT[i] = f2bf(w);
  }
  if (i < 384 * 384) {                   // woutT[n][k] = wout[k][n]
    int n = i / 384, k = i - (i / 384) * 384;
    woutT[i] = f2bf(wout[k * 384 + n]);
  }
}

// bias table: btabT[t][i][c][nt] = bias(i, j=nt*16+c) for window-type t
__global__ void prep_bias(const float* __restrict__ pe, float* __restrict__ btabT) {
  int id = blockIdx.x * 256 + threadIdx.x;   // 4*64*64
  if (id >= 16384) return;
  int t = id >> 12;
  int i = (id >> 6) & 63;
  int j = id & 63;
  float v;
  if (i < 49 && j < 49) {
    int ai = i / 7, bi = i - ai * 7, aj = j / 7, bj = j - aj * 7;
    v = pe[(aj - ai + 6) * 13 + (bj - bi + 6)];
    if ((t & 1) && ((i >= 28) != (j >= 28))) v = -1e30f;
    if ((t & 2) && ((bi >= 4) != (bj >= 4))) v = -1e30f;
  } else if (j < 49) {
    v = 0.f;
  } else {
    v = -1e30f;
  }
  btabT[((t * 64 + i) * 16 + (j & 15)) * 4 + (j >> 4)] = v;
}

// depth-2 pipelined 12-step K-loop over 3 rotating B buffers (all indices compile-time)
#define GEMM_STEP(BUF)                                                        \
  {                                                                           \
    short8 a0 = *(const short8*)(pA[0] + k * 32);                             \
    short8 a1 = *(const short8*)(pA[1] + k * 32);                             \
    short8 a2 = *(const short8*)(pA[2] + k * 32);                             \
    short8 a3 = *(const short8*)(pA[3] + k * 32);                             \
    acc[0][0] = MFMA(a0, BUF[0], acc[0][0]);                                  \
    acc[1][0] = MFMA(a1, BUF[0], acc[1][0]);                                  \
    acc[2][0] = MFMA(a2, BUF[0], acc[2][0]);                                  \
    acc[3][0] = MFMA(a3, BUF[0], acc[3][0]);                                  \
    acc[0][1] = MFMA(a0, BUF[1], acc[0][1]);                                  \
    acc[1][1] = MFMA(a1, BUF[1], acc[1][1]);                                  \
    acc[2][1] = MFMA(a2, BUF[1], acc[2][1]);                                  \
    acc[3][1] = MFMA(a3, BUF[1], acc[3][1]);                                  \
    acc[0][2] = MFMA(a0, BUF[2], acc[0][2]);                                  \
    acc[1][2] = MFMA(a1, BUF[2], acc[1][2]);                                  \
    acc[2][2] = MFMA(a2, BUF[2], acc[2][2]);                                  \
    acc[3][2] = MFMA(a3, BUF[2], acc[3][2]);                                  \
  }

#define GEMM_PIPELINE()                                                       \
  _Pragma("unroll")                                                           \
  for (int n = 0; n < 3; ++n) bA[n] = *(const short8*)(pB[n]);                \
  _Pragma("unroll")                                                           \
  for (int n = 0; n < 3; ++n) bB[n] = *(const short8*)(pB[n] + 32);           \
  _Pragma("unroll")                                                           \
  for (int k = 0; k < 12; ++k) {                                              \
    if (k + 2 < 12) {                                                         \
      const int off = (k + 2) * 32;                                           \
      if (k % 3 == 0) {                                                       \
        _Pragma("unroll")                                                     \
        for (int n = 0; n < 3; ++n) bC[n] = *(const short8*)(pB[n] + off);    \
      } else if (k % 3 == 1) {                                                \
        _Pragma("unroll")                                                     \
        for (int n = 0; n < 3; ++n) bA[n] = *(const short8*)(pB[n] + off);    \
      } else {                                                                \
        _Pragma("unroll")                                                     \
        for (int n = 0; n < 3; ++n) bB[n] = *(const short8*)(pB[n] + off);    \
      }                                                                       \
    }                                                                         \
    if (k % 3 == 0) GEMM_STEP(bA)                                             \
    else if (k % 3 == 1) GEMM_STEP(bB)                                        \
    else GEMM_STEP(bC)                                                        \
  }

// ---------------- K1: QKV GEMM (4-head slice) + windowed attention ----------------
__global__ __launch_bounds__(512, 4) void swin_qkv_attn(
    const float* __restrict__ x, const short* __restrict__ wqkvT,
    const float* __restrict__ btabT, short* __restrict__ aout) {

  __shared__ short xs[49 * XS_STR];   // 38,416 B; aliased by Pbuf in phase 3
  __shared__ short qk[49 * QK_STR];   // 25,872 B: cols 0..127 Q | 128..255 K
  __shared__ short vT[128 * 64];      // 16,384 B: vT[d][j], byte ^= (d&7)<<4 swizzle

  const int tid = threadIdx.x;
  const int lane = tid & 63;
  const int wv = tid >> 6;
  const int l15 = lane & 15;
  const int lhi = lane >> 4;

  // XCD-chunked bijective swizzle (6144 % 8 == 0)
  const int bid = blockIdx.x;
  const int sw = (bid & 7) * 768 + (bid >> 3);
  const int g = sw - (sw / 3) * 3;
  const int bw = sw / 3;
  const int batch = bw >> 6;
  const int win = bw & 63;
  const int wy = win >> 3, wx = win & 7;

  const size_t xbase = (size_t)batch * (56 * 56 * 384);
  const f32x4 zf = {0.f, 0.f, 0.f, 0.f};

  // zero vT (covers garbage rows j>=49)
  {
    int* vz = (int*)vT;
    for (int t2 = tid; t2 < 4096; t2 += 512) vz[t2] = 0;
  }

  // Phase 1: load shifted x window -> xs (bf16 via cvt_pk)
  for (int t = tid; t < 49 * 96; t += 512) {
    int tok = t / 96;
    int seg = t - tok * 96;
    int iy = (tok * 37) >> 8;
    int ix = tok - iy * 7;
    int r = wy * 7 + iy + 3; if (r >= 56) r -= 56;
    int c = wx * 7 + ix + 3; if (c >= 56) c -= 56;
    const float4 v = *(const float4*)(x + xbase + (size_t)(r * 56 + c) * 384 + seg * 4);
    int2v o;
    o.x = (int)cvt_pk(v.x, v.y);
    o.y = (int)cvt_pk(v.z, v.w);
    *(int2v*)(&xs[tok * XS_STR + seg * 4]) = o;
  }
  __syncthreads();

  // Phase 2: QKV GEMM for head group g: 49x384 @ 384x384 (depth-2 pipelined B)
  {
    const int n0 = wv * 48;
    const short* pB[3];
#pragma unroll
    for (int n = 0; n < 3; ++n) {
      const int c0 = n0 + n * 16;
      const int seg = c0 >> 7;             // 0=q 1=k 2=v
      const int hloc = (c0 >> 5) & 3;
      const int wrow = seg * 384 + (g * 4 + hloc) * 32 + (c0 & 31);
      pB[n] = wqkvT + (size_t)(wrow + l15) * 384 + lhi * 8;
    }
    f32x4 acc[4][3];
#pragma unroll
    for (int m = 0; m < 4; ++m)
#pragma unroll
      for (int n = 0; n < 3; ++n) acc[m][n] = zf;

    const short* pA[4];
#pragma unroll
    for (int m = 0; m < 4; ++m) {
      int row = m * 16 + l15;
      int rc = row < 49 ? row : 48;
      pA[m] = &xs[rc * XS_STR + lhi * 8];
    }

    short8 bA[3], bB[3], bC[3];
    GEMM_PIPELINE()

    // epilogue: Q (pre-scaled) and K -> qk, V -> vT (transposed + swizzled)
#pragma unroll
    for (int n = 0; n < 3; ++n) {
      const int c0 = n0 + n * 16;
#pragma unroll
      for (int m = 0; m < 4; ++m)
#pragma unroll
        for (int r = 0; r < 4; ++r) {
          int row = m * 16 + lhi * 4 + r;
          if (row < 49) {
            if (c0 < 256) {
              qk[row * QK_STR + c0 + l15] = f2bf(acc[m][n][r]);
            } else {
              const int d = c0 - 256 + l15;
              *(short*)((char*)vT + d * 128 + ((2 * row) ^ ((d & 7) << 4))) =
                  f2bf(acc[m][n][r]);
            }
          }
        }
    }
  }
  __syncthreads();

  // Phase 3: attention — one task per wave: head hl = wv>>1, row-half mh = wv&1
  {
    const int hl = wv >> 1;
    const int mh = wv & 1;
    const int tt = (wy == 7 ? 1 : 0) | (wx == 7 ? 2 : 0);
    short* Pbuf = &xs[wv * 2304];   // wave-private 32 x P_STR (xs dead)

    // bias loads (independent of S — issue early)
    f32x4 bb[2][4];
#pragma unroll
    for (int mi = 0; mi < 2; ++mi)
#pragma unroll
      for (int r = 0; r < 4; ++r) {
        const int i = mh * 32 + mi * 16 + lhi * 4 + r;
        bb[mi][r] = *(const f32x4*)(&btabT[((tt * 64 + i) * 16 + l15) * 4]);
      }

    short8 qa[2];
#pragma unroll
    for (int mi = 0; mi < 2; ++mi) {
      int row = mh * 32 + mi * 16 + l15;
      int rc = row < 49 ? row : 48;
      qa[mi] = *(const short8*)(&qk[rc * QK_STR + hl * 32 + lhi * 8]);
    }
    f32x4 s[2][4];
#pragma unroll
    for (int nt = 0; nt < 4; ++nt) {
      int jr = nt * 16 + l15;
      int jc = jr < 49 ? jr : 48;          // garbage cols killed by bias -1e30
      short8 kb = *(const short8*)(&qk[jc * QK_STR + 128 + hl * 32 + lhi * 8]);
#pragma unroll
      for (int mi = 0; mi < 2; ++mi) s[mi][nt] = MFMA(qa[mi], kb, zf);
    }

    // bias add (scale pre-folded into Q weights)
#pragma unroll
    for (int mi = 0; mi < 2; ++mi)
#pragma unroll
      for (int r = 0; r < 4; ++r)
#pragma unroll
        for (int nt = 0; nt < 4; ++nt)
          s[mi][nt][r] += bb[mi][r][nt];

    // softmax per row
#pragma unroll
    for (int mi = 0; mi < 2; ++mi)
#pragma unroll
      for (int r = 0; r < 4; ++r) {
        float mx = fmaxf(fmaxf(s[mi][0][r], s[mi][1][r]),
                         fmaxf(s[mi][2][r], s[mi][3][r]));
        mx = fmaxf(mx, __shfl_xor(mx, 1));
        mx = fmaxf(mx, __shfl_xor(mx, 2));
        mx = fmaxf(mx, __shfl_xor(mx, 4));
        mx = fmaxf(mx, __shfl_xor(mx, 8));
        float p0 = __expf(s[mi][0][r] - mx);
        float p1 = __expf(s[mi][1][r] - mx);
        float p2 = __expf(s[mi][2][r] - mx);
        float p3 = __expf(s[mi][3][r] - mx);
        float sum = p0 + p1 + p2 + p3;
        sum += __shfl_xor(sum, 1);
        sum += __shfl_xor(sum, 2);
        sum += __shfl_xor(sum, 4);
        sum += __shfl_xor(sum, 8);
        const float inv = __builtin_amdgcn_rcpf(sum);
        const int rowl = mi * 16 + lhi * 4 + r;
        Pbuf[rowl * P_STR +  0 + l15] = f2bf(p0 * inv);
        Pbuf[rowl * P_STR + 16 + l15] = f2bf(p1 * inv);
        Pbuf[rowl * P_STR + 32 + l15] = f2bf(p2 * inv);
        Pbuf[rowl * P_STR + 48 + l15] = f2bf(p3 * inv);
      }

    f32x4 O[2][2];
#pragma unroll
    for (int mi = 0; mi < 2; ++mi)
#pragma unroll
      for (int n2 = 0; n2 < 2; ++n2) O[mi][n2] = zf;

#pragma unroll
    for (int ks = 0; ks < 2; ++ks) {
      short8 pa[2];
#pragma unroll
      for (int mi = 0; mi < 2; ++mi)
        pa[mi] = *(const short8*)(&Pbuf[(mi * 16 + l15) * P_STR + ks * 32 + lhi * 8]);
#pragma unroll
      for (int n2 = 0; n2 < 2; ++n2) {
        const int dg = hl * 32 + n2 * 16 + l15;
        const short8 vb = *(const short8*)((const char*)vT + dg * 128 +
                              ((ks * 64 + lhi * 16) ^ ((dg & 7) << 4)));
#pragma unroll
        for (int mi = 0; mi < 2; ++mi) O[mi][n2] = MFMA(pa[mi], vb, O[mi][n2]);
      }
    }

    short* ab = aout + (size_t)bw * (49 * 384) + (g * 4 + hl) * 32;
#pragma unroll
    for (int mi = 0; mi < 2; ++mi)
#pragma unroll
      for (int n2 = 0; n2 < 2; ++n2)
#pragma unroll
        for (int r = 0; r < 4; ++r) {
          int row = mh * 32 + mi * 16 + lhi * 4 + r;
          if (row < 49) ab[row * 384 + n2 * 16 + l15] = f2bf(O[mi][n2][r]);
        }
  }
}

// ---------------- K2: out-proj (49x384 @ 384x384) + bias + inverse roll ----------------
__global__ __launch_bounds__(512, 4) void swin_outproj(
    const short* __restrict__ aout, const short* __restrict__ woutT,
    const float* __restrict__ bout, float* __restrict__ out) {

  __shared__ short ao[49 * AO_STR];   // 38,416 B

  const int tid = threadIdx.x;
  const int lane = tid & 63;
  const int wv = tid >> 6;
  const int l15 = lane & 15;
  const int lhi = lane >> 4;

  const int bw = blockIdx.x;
  const int batch = bw >> 6;
  const int win = bw & 63;
  const int wy = win >> 3, wx = win & 7;

  const size_t xbase = (size_t)batch * (56 * 56 * 384);
  const f32x4 zf = {0.f, 0.f, 0.f, 0.f};

  const short* abg = aout + (size_t)bw * (49 * 384);
  for (int t = tid; t < 49 * 48; t += 512) {
    int row = t / 48;
    int seg = t - row * 48;
    *(short8*)(&ao[row * AO_STR + seg * 8]) = *(const short8*)(&abg[row * 384 + seg * 8]);
  }
  __syncthreads();

  {
    const int n0 = wv * 48;
    f32x4 acc[4][3];
#pragma unroll
    for (int m = 0; m < 4; ++m)
#pragma unroll
      for (int n = 0; n < 3; ++n) acc[m][n] = zf;

    const short* pB[3];
#pragma unroll
    for (int n = 0; n < 3; ++n)
      pB[n] = woutT + (size_t)(n0 + n * 16 + l15) * 384 + lhi * 8;

    const short* pA[4];
#pragma unroll
    for (int m = 0; m < 4; ++m) {
      int row = m * 16 + l15;
      int rc = row < 49 ? row : 48;
      pA[m] = &ao[rc * AO_STR + lhi * 8];
    }

    short8 bA[3], bB[3], bC[3];
    GEMM_PIPELINE()

    float bo[3];
#pragma unroll
    for (int n = 0; n < 3; ++n) bo[n] = bout[n0 + n * 16 + l15];

#pragma unroll
    for (int m = 0; m < 4; ++m)
#pragma unroll
      for (int r = 0; r < 4; ++r) {
        const int row = m * 16 + lhi * 4 + r;
        if (row < 49) {
          int iy = (row * 37) >> 8, ix = row - iy * 7;
          int rr = wy * 7 + iy + 3; if (rr >= 56) rr -= 56;
          int cc = wx * 7 + ix + 3; if (cc >= 56) cc -= 56;
          float* dst = out + xbase + (size_t)(rr * 56 + cc) * 384 + n0;
#pragma unroll
          for (int n = 0; n < 3; ++n) dst[n * 16 + l15] = acc[m][n][r] + bo[n];
        }
      }
  }
}

extern "C" void kernel_launch(void* const* d_in, const int* in_sizes, int n_in,
                              void* d_out, int out_size, void* d_ws, size_t ws_size,
                              hipStream_t stream) {
  const float* x    = (const float*)d_in[0];
  const float* wqkv = (const float*)d_in[1];
  const float* pos  = (const float*)d_in[2];
  const float* wout = (const float*)d_in[3];
  const float* bo   = (const float*)d_in[4];

  char* ws = (char*)d_ws;
  short* wqkvT = (short*)ws;                         ws += 1152 * 384 * 2;
  short* woutT = (short*)ws;                         ws += 384 * 384 * 2;
  float* btabT = (float*)ws;                         ws += 4 * 64 * 16 * 4 * 4;
  short* aoutg = (short*)ws;                         // [2048][49][384] bf16 (~77 MB)

  prep_weights<<<1728, 256, 0, stream>>>(wqkv, wout, wqkvT, woutT);
  prep_bias<<<64, 256, 0, stream>>>(pos, btabT);
  swin_qkv_attn<<<6144, 512, 0, stream>>>(x, wqkvT, btabT, aoutg);
  swin_outproj<<<2048, 512, 0, stream>>>(aoutg, woutT, bo, (float*)d_out);
}